// Round 1
// baseline (1494.507 us; speedup 1.0000x reference)
//
#include <hip/hip_runtime.h>
#include <hip/hip_bf16.h>

#define IN_FT 128
#define OUT_FT 64

// ---------------------------------------------------------------------------
// Kernel 1: h = x @ W + b   (fp32, vector ALU — no fp32 MFMA on CDNA4)
// 64 rows/block, W (128x64, 32KB) + x tile (64x128, padded stride 132) in LDS,
// each thread computes a 4x4 output tile (rows 4rg..+3, cols 4jg..+3).
// ---------------------------------------------------------------------------
constexpr int ROWS_PER_BLOCK = 64;
constexpr int XS_STRIDE = 132;   // pad 128->132: breaks 512-word same-bank stride, keeps 16B align

__global__ __launch_bounds__(256) void gcn_fc_kernel(
    const float* __restrict__ x, const float* __restrict__ W,
    const float* __restrict__ b, float* __restrict__ h, int N)
{
    __shared__ float Wl[IN_FT * OUT_FT];              // 32768 B
    __shared__ float xs[ROWS_PER_BLOCK * XS_STRIDE];  // 33792 B

    const int tid  = threadIdx.x;
    const int row0 = blockIdx.x * ROWS_PER_BLOCK;

    // stage W: 8192 floats = 2048 float4, coalesced
    for (int i = tid; i < (IN_FT * OUT_FT) / 4; i += 256) {
        reinterpret_cast<float4*>(Wl)[i] = reinterpret_cast<const float4*>(W)[i];
    }
    // stage x tile: 64 rows x 128, coalesced float4, zero-pad tail rows
    for (int i = tid; i < (ROWS_PER_BLOCK * IN_FT) / 4; i += 256) {
        const int r  = i / (IN_FT / 4);
        const int c4 = i % (IN_FT / 4);
        float4 v = make_float4(0.f, 0.f, 0.f, 0.f);
        if (row0 + r < N)
            v = reinterpret_cast<const float4*>(x + (size_t)(row0 + r) * IN_FT)[c4];
        reinterpret_cast<float4*>(&xs[r * XS_STRIDE])[c4] = v;
    }
    __syncthreads();

    const int jg = tid & 15;   // col group: cols 4jg..4jg+3
    const int rg = tid >> 4;   // row group: rows 4rg..4rg+3

    const float4 bv = reinterpret_cast<const float4*>(b)[jg];
    float acc[4][4];
#pragma unroll
    for (int rr = 0; rr < 4; ++rr) {
        acc[rr][0] = bv.x; acc[rr][1] = bv.y; acc[rr][2] = bv.z; acc[rr][3] = bv.w;
    }

    for (int k0 = 0; k0 < IN_FT; k0 += 4) {
        float wf[4][4];
#pragma unroll
        for (int kk = 0; kk < 4; ++kk) {
            const float4 t = *reinterpret_cast<const float4*>(&Wl[(k0 + kk) * OUT_FT + 4 * jg]);
            wf[kk][0] = t.x; wf[kk][1] = t.y; wf[kk][2] = t.z; wf[kk][3] = t.w;
        }
#pragma unroll
        for (int rr = 0; rr < 4; ++rr) {
            const float4 xv = *reinterpret_cast<const float4*>(&xs[(4 * rg + rr) * XS_STRIDE + k0]);
            const float xk[4] = {xv.x, xv.y, xv.z, xv.w};
#pragma unroll
            for (int kk = 0; kk < 4; ++kk) {
#pragma unroll
                for (int jj = 0; jj < 4; ++jj)
                    acc[rr][jj] += xk[kk] * wf[kk][jj];
            }
        }
    }

#pragma unroll
    for (int rr = 0; rr < 4; ++rr) {
        const int r = row0 + 4 * rg + rr;
        if (r < N) {
            const float4 o = make_float4(acc[rr][0], acc[rr][1], acc[rr][2], acc[rr][3]);
            *reinterpret_cast<float4*>(&h[(size_t)r * OUT_FT + 4 * jg]) = o;
        }
    }
}

// ---------------------------------------------------------------------------
// Kernel 2: edge scatter  out[row[e]] += val[e] * h[col[e]]
// 16 threads per edge, float4 gather of h, 4x atomicAdd f32 per thread.
// ---------------------------------------------------------------------------
__global__ __launch_bounds__(256) void gcn_scatter_kernel(
    const float* __restrict__ h, const int* __restrict__ erow,
    const int* __restrict__ ecol, const float* __restrict__ eval_,
    float* __restrict__ out, int E)
{
    const int t  = blockIdx.x * blockDim.x + threadIdx.x;
    const int e  = t >> 4;           // 16 threads per edge
    const int fg = (t & 15) * 4;     // feature offset 0,4,...,60
    if (e >= E) return;

    const int   col = ecol[e];
    const int   row = erow[e];
    const float v   = eval_[e];

    const float4 hv = *reinterpret_cast<const float4*>(&h[(size_t)col * OUT_FT + fg]);
    float* op = &out[(size_t)row * OUT_FT + fg];
    atomicAdd(op + 0, v * hv.x);
    atomicAdd(op + 1, v * hv.y);
    atomicAdd(op + 2, v * hv.z);
    atomicAdd(op + 3, v * hv.w);
}

// ---------------------------------------------------------------------------
// Kernel 3: shared-slope PReLU in-place on out
// ---------------------------------------------------------------------------
__global__ __launch_bounds__(256) void gcn_prelu_kernel(
    float* __restrict__ out, const float* __restrict__ alpha, int n4)
{
    const float a = alpha[0];
    for (int i = blockIdx.x * blockDim.x + threadIdx.x; i < n4;
         i += gridDim.x * blockDim.x) {
        float4 v = reinterpret_cast<float4*>(out)[i];
        v.x = v.x >= 0.f ? v.x : a * v.x;
        v.y = v.y >= 0.f ? v.y : a * v.y;
        v.z = v.z >= 0.f ? v.z : a * v.z;
        v.w = v.w >= 0.f ? v.w : a * v.w;
        reinterpret_cast<float4*>(out)[i] = v;
    }
}

extern "C" void kernel_launch(void* const* d_in, const int* in_sizes, int n_in,
                              void* d_out, int out_size, void* d_ws, size_t ws_size,
                              hipStream_t stream)
{
    const float* x     = (const float*)d_in[0];
    const float* W     = (const float*)d_in[1];
    const float* b     = (const float*)d_in[2];
    const float* alpha = (const float*)d_in[3];
    const int*   erow  = (const int*)d_in[4];
    const int*   ecol  = (const int*)d_in[5];
    const float* eval_ = (const float*)d_in[6];
    float* out = (float*)d_out;

    const int N = in_sizes[0] / IN_FT;   // 100000
    const int E = in_sizes[4];           // 1600000

    float* h = (float*)d_ws;             // N * 64 * 4 = 25.6 MB scratch

    // out is poisoned 0xAA before every timed launch -> zero it for the atomics
    hipMemsetAsync(d_out, 0, (size_t)N * OUT_FT * sizeof(float), stream);

    gcn_fc_kernel<<<(N + ROWS_PER_BLOCK - 1) / ROWS_PER_BLOCK, 256, 0, stream>>>(
        x, W, b, h, N);

    const long long scatter_threads = (long long)E * 16;
    gcn_scatter_kernel<<<(scatter_threads + 255) / 256, 256, 0, stream>>>(
        h, erow, ecol, eval_, out, E);

    gcn_prelu_kernel<<<2048, 256, 0, stream>>>(out, alpha, (N * OUT_FT) / 4);
}

// Round 3
// 380.808 us; speedup vs baseline: 3.9246x; 3.9246x over previous
//
#include <hip/hip_runtime.h>
#include <hip/hip_bf16.h>

#define IN_FT 128
#define OUT_FT 64

// ===========================================================================
// Kernel 1: h = x @ W + b   (fp32, vector ALU — no fp32 MFMA on CDNA4)
// ===========================================================================
constexpr int ROWS_PER_BLOCK = 64;
constexpr int XS_STRIDE = 132;

__global__ __launch_bounds__(256) void gcn_fc_kernel(
    const float* __restrict__ x, const float* __restrict__ W,
    const float* __restrict__ b, float* __restrict__ h, int N)
{
    __shared__ float Wl[IN_FT * OUT_FT];
    __shared__ float xs[ROWS_PER_BLOCK * XS_STRIDE];

    const int tid  = threadIdx.x;
    const int row0 = blockIdx.x * ROWS_PER_BLOCK;

    for (int i = tid; i < (IN_FT * OUT_FT) / 4; i += 256)
        reinterpret_cast<float4*>(Wl)[i] = reinterpret_cast<const float4*>(W)[i];

    for (int i = tid; i < (ROWS_PER_BLOCK * IN_FT) / 4; i += 256) {
        const int r  = i / (IN_FT / 4);
        const int c4 = i % (IN_FT / 4);
        float4 v = make_float4(0.f, 0.f, 0.f, 0.f);
        if (row0 + r < N)
            v = reinterpret_cast<const float4*>(x + (size_t)(row0 + r) * IN_FT)[c4];
        reinterpret_cast<float4*>(&xs[r * XS_STRIDE])[c4] = v;
    }
    __syncthreads();

    const int jg = tid & 15;
    const int rg = tid >> 4;

    const float4 bv = reinterpret_cast<const float4*>(b)[jg];
    float acc[4][4];
#pragma unroll
    for (int rr = 0; rr < 4; ++rr) {
        acc[rr][0] = bv.x; acc[rr][1] = bv.y; acc[rr][2] = bv.z; acc[rr][3] = bv.w;
    }

    for (int k0 = 0; k0 < IN_FT; k0 += 4) {
        float wf[4][4];
#pragma unroll
        for (int kk = 0; kk < 4; ++kk) {
            const float4 t = *reinterpret_cast<const float4*>(&Wl[(k0 + kk) * OUT_FT + 4 * jg]);
            wf[kk][0] = t.x; wf[kk][1] = t.y; wf[kk][2] = t.z; wf[kk][3] = t.w;
        }
#pragma unroll
        for (int rr = 0; rr < 4; ++rr) {
            const float4 xv = *reinterpret_cast<const float4*>(&xs[(4 * rg + rr) * XS_STRIDE + k0]);
            const float xk[4] = {xv.x, xv.y, xv.z, xv.w};
#pragma unroll
            for (int kk = 0; kk < 4; ++kk)
#pragma unroll
                for (int jj = 0; jj < 4; ++jj)
                    acc[rr][jj] += xk[kk] * wf[kk][jj];
        }
    }

#pragma unroll
    for (int rr = 0; rr < 4; ++rr) {
        const int r = row0 + 4 * rg + rr;
        if (r < N)
            *reinterpret_cast<float4*>(&h[(size_t)r * OUT_FT + 4 * jg]) =
                make_float4(acc[rr][0], acc[rr][1], acc[rr][2], acc[rr][3]);
    }
}

// ===========================================================================
// CSR build: count -> scan(3 kernels) -> fill (1 int atomic per edge)
// ===========================================================================
__global__ __launch_bounds__(256) void k_count(
    const int* __restrict__ erow, int* __restrict__ cnt, int E)
{
    const int e = blockIdx.x * blockDim.x + threadIdx.x;
    if (e < E) atomicAdd(&cnt[erow[e]], 1);
}

// chunk = 1024 elements/block; 256 threads x 4 elements each
__global__ __launch_bounds__(256) void k_scanA(
    const int* __restrict__ cnt, int* __restrict__ rptr,
    int* __restrict__ bsum, int N)
{
    __shared__ int s[256];
    const int t   = threadIdx.x;
    const int idx = blockIdx.x * 1024 + t * 4;

    int4 v = make_int4(0, 0, 0, 0);
    if (idx + 3 < N) v = *reinterpret_cast<const int4*>(&cnt[idx]);
    else {
        if (idx     < N) v.x = cnt[idx];
        if (idx + 1 < N) v.y = cnt[idx + 1];
        if (idx + 2 < N) v.z = cnt[idx + 2];
        if (idx + 3 < N) v.w = cnt[idx + 3];
    }
    const int tsum = v.x + v.y + v.z + v.w;
    s[t] = tsum;
    __syncthreads();
    for (int d = 1; d < 256; d <<= 1) {
        const int o = (t >= d) ? s[t - d] : 0;
        __syncthreads();
        s[t] += o;
        __syncthreads();
    }
    const int excl = s[t] - tsum;
    const int p0 = excl, p1 = p0 + v.x, p2 = p1 + v.y, p3 = p2 + v.z;
    if (idx     < N) rptr[idx]     = p0;
    if (idx + 1 < N) rptr[idx + 1] = p1;
    if (idx + 2 < N) rptr[idx + 2] = p2;
    if (idx + 3 < N) rptr[idx + 3] = p3;
    if (t == 255) bsum[blockIdx.x] = s[255];
}

// single block scans up to 1024 block sums (exclusive)
__global__ __launch_bounds__(1024) void k_scanB(int* __restrict__ bsum, int nb)
{
    __shared__ int s[1024];
    const int t = threadIdx.x;
    const int v = (t < nb) ? bsum[t] : 0;
    s[t] = v;
    __syncthreads();
    for (int d = 1; d < 1024; d <<= 1) {
        const int o = (t >= d) ? s[t - d] : 0;
        __syncthreads();
        s[t] += o;
        __syncthreads();
    }
    if (t < nb) bsum[t] = s[t] - v;
}

__global__ __launch_bounds__(256) void k_scanC(
    int* __restrict__ rptr, const int* __restrict__ bsum, int N)
{
    const int i = blockIdx.x * blockDim.x + threadIdx.x;
    if (i < N) rptr[i] += bsum[i >> 10];
}

__global__ __launch_bounds__(256) void k_fill(
    const int* __restrict__ erow, const int* __restrict__ ecol,
    const float* __restrict__ eval_, int* __restrict__ cursor,
    int* __restrict__ colS, float* __restrict__ valS, int E)
{
    const int e = blockIdx.x * blockDim.x + threadIdx.x;
    if (e >= E) return;
    const int r   = erow[e];
    const int pos = atomicAdd(&cursor[r], 1);
    colS[pos] = ecol[e];
    valS[pos] = eval_[e];
}

// ===========================================================================
// Gather: one wave per row, lane = feature. PReLU fused in epilogue.
// ===========================================================================
__global__ __launch_bounds__(256) void k_gather(
    const float* __restrict__ h, const int* __restrict__ rptr,
    const int* __restrict__ cnt, const int* __restrict__ colS,
    const float* __restrict__ valS, const float* __restrict__ alpha,
    float* __restrict__ out, int N)
{
    const int wid  = (int)((blockIdx.x * (size_t)blockDim.x + threadIdx.x) >> 6);
    const int lane = threadIdx.x & 63;
    if (wid >= N) return;

    const int start = rptr[wid];
    const int deg   = cnt[wid];

    float acc = 0.f;
    int j = 0;
    for (; j + 4 <= deg; j += 4) {
        const int   c0 = colS[start + j + 0], c1 = colS[start + j + 1];
        const int   c2 = colS[start + j + 2], c3 = colS[start + j + 3];
        const float v0 = valS[start + j + 0], v1 = valS[start + j + 1];
        const float v2 = valS[start + j + 2], v3 = valS[start + j + 3];
        const float h0 = h[(size_t)c0 * OUT_FT + lane];
        const float h1 = h[(size_t)c1 * OUT_FT + lane];
        const float h2 = h[(size_t)c2 * OUT_FT + lane];
        const float h3 = h[(size_t)c3 * OUT_FT + lane];
        acc += v0 * h0; acc += v1 * h1; acc += v2 * h2; acc += v3 * h3;
    }
    for (; j < deg; ++j) {
        const int   c = colS[start + j];
        const float v = valS[start + j];
        acc += v * h[(size_t)c * OUT_FT + lane];
    }

    const float a = alpha[0];
    out[(size_t)wid * OUT_FT + lane] = (acc >= 0.f) ? acc : a * acc;
}

// ===========================================================================
// Fallback scatter (old atomic path) if ws too small for CSR
// ===========================================================================
__global__ __launch_bounds__(256) void gcn_scatter_kernel(
    const float* __restrict__ h, const int* __restrict__ erow,
    const int* __restrict__ ecol, const float* __restrict__ eval_,
    float* __restrict__ out, int E)
{
    const int t  = blockIdx.x * blockDim.x + threadIdx.x;
    const int e  = t >> 4;
    const int fg = (t & 15) * 4;
    if (e >= E) return;
    const int   col = ecol[e];
    const int   row = erow[e];
    const float v   = eval_[e];
    const float4 hv = *reinterpret_cast<const float4*>(&h[(size_t)col * OUT_FT + fg]);
    float* op = &out[(size_t)row * OUT_FT + fg];
    atomicAdd(op + 0, v * hv.x);
    atomicAdd(op + 1, v * hv.y);
    atomicAdd(op + 2, v * hv.z);
    atomicAdd(op + 3, v * hv.w);
}

__global__ __launch_bounds__(256) void gcn_prelu_kernel(
    float* __restrict__ out, const float* __restrict__ alpha, int n4)
{
    const float a = alpha[0];
    for (int i = blockIdx.x * blockDim.x + threadIdx.x; i < n4;
         i += gridDim.x * blockDim.x) {
        float4 v = reinterpret_cast<float4*>(out)[i];
        v.x = v.x >= 0.f ? v.x : a * v.x;
        v.y = v.y >= 0.f ? v.y : a * v.y;
        v.z = v.z >= 0.f ? v.z : a * v.z;
        v.w = v.w >= 0.f ? v.w : a * v.w;
        reinterpret_cast<float4*>(out)[i] = v;
    }
}

// ===========================================================================
extern "C" void kernel_launch(void* const* d_in, const int* in_sizes, int n_in,
                              void* d_out, int out_size, void* d_ws, size_t ws_size,
                              hipStream_t stream)
{
    const float* x     = (const float*)d_in[0];
    const float* W     = (const float*)d_in[1];
    const float* b     = (const float*)d_in[2];
    const float* alpha = (const float*)d_in[3];
    const int*   erow  = (const int*)d_in[4];
    const int*   ecol  = (const int*)d_in[5];
    const float* eval_ = (const float*)d_in[6];
    float* out = (float*)d_out;

    const int N = in_sizes[0] / IN_FT;   // 100000
    const int E = in_sizes[4];           // 1600000

    // ---- workspace layout (16B aligned slices) ----
    char* ws = (char*)d_ws;
    const size_t hB    = (size_t)N * OUT_FT * sizeof(float);          // 25.6 MB
    const size_t nIB   = ((size_t)N * sizeof(int) + 15) & ~15ull;     // 400 KB
    const int    nbA   = (N + 1023) / 1024;                           // scan blocks (<=1024)
    const size_t bsB   = ((size_t)nbA * sizeof(int) + 15) & ~15ull;
    const size_t eIB   = ((size_t)E * sizeof(int) + 15) & ~15ull;     // 6.4 MB
    const size_t eFB   = ((size_t)E * sizeof(float) + 15) & ~15ull;   // 6.4 MB

    float* h      = (float*)ws;                 size_t off = hB;
    int*   rptr   = (int*)(ws + off);           off += nIB;
    int*   cursor = (int*)(ws + off);           off += nIB;
    int*   cnt    = (int*)(ws + off);           off += nIB;
    int*   bsum   = (int*)(ws + off);           off += bsB;
    int*   colS   = (int*)(ws + off);           off += eIB;
    float* valS   = (float*)(ws + off);         off += eFB;
    const bool csr_ok = (off <= ws_size) && (nbA <= 1024);

    // FC: h = xW + b
    gcn_fc_kernel<<<(N + ROWS_PER_BLOCK - 1) / ROWS_PER_BLOCK, 256, 0, stream>>>(
        x, W, b, h, N);

    if (csr_ok) {
        hipMemsetAsync(cnt, 0, (size_t)N * sizeof(int), stream);
        k_count<<<(E + 255) / 256, 256, 0, stream>>>(erow, cnt, E);
        k_scanA<<<nbA, 256, 0, stream>>>(cnt, rptr, bsum, N);
        k_scanB<<<1, 1024, 0, stream>>>(bsum, nbA);
        k_scanC<<<(N + 255) / 256, 256, 0, stream>>>(rptr, bsum, N);
        hipMemcpyAsync(cursor, rptr, (size_t)N * sizeof(int),
                       hipMemcpyDeviceToDevice, stream);
        k_fill<<<(E + 255) / 256, 256, 0, stream>>>(
            erow, ecol, eval_, cursor, colS, valS, E);
        const size_t gthreads = (size_t)N * 64;
        k_gather<<<(int)((gthreads + 255) / 256), 256, 0, stream>>>(
            h, rptr, cnt, colS, valS, alpha, out, N);
    } else {
        hipMemsetAsync(d_out, 0, (size_t)N * OUT_FT * sizeof(float), stream);
        const long long st = (long long)E * 16;
        gcn_scatter_kernel<<<(st + 255) / 256, 256, 0, stream>>>(
            h, erow, ecol, eval_, out, E);
        gcn_prelu_kernel<<<2048, 256, 0, stream>>>(out, alpha, (N * OUT_FT) / 4);
    }
}

// Round 4
// 315.028 us; speedup vs baseline: 4.7440x; 1.2088x over previous
//
#include <hip/hip_runtime.h>
#include <hip/hip_bf16.h>

#define IN_FT 128
#define OUT_FT 64

// ===========================================================================
// FC: h = x @ W + b   (fp32, vector ALU — no fp32 MFMA on CDNA4)
// ===========================================================================
constexpr int ROWS_PER_BLOCK = 64;
constexpr int XS_STRIDE = 132;

__global__ __launch_bounds__(256) void gcn_fc_kernel(
    const float* __restrict__ x, const float* __restrict__ W,
    const float* __restrict__ b, float* __restrict__ h, int N)
{
    __shared__ float Wl[IN_FT * OUT_FT];
    __shared__ float xs[ROWS_PER_BLOCK * XS_STRIDE];

    const int tid  = threadIdx.x;
    const int row0 = blockIdx.x * ROWS_PER_BLOCK;

    for (int i = tid; i < (IN_FT * OUT_FT) / 4; i += 256)
        reinterpret_cast<float4*>(Wl)[i] = reinterpret_cast<const float4*>(W)[i];

    for (int i = tid; i < (ROWS_PER_BLOCK * IN_FT) / 4; i += 256) {
        const int r  = i / (IN_FT / 4);
        const int c4 = i % (IN_FT / 4);
        float4 v = make_float4(0.f, 0.f, 0.f, 0.f);
        if (row0 + r < N)
            v = reinterpret_cast<const float4*>(x + (size_t)(row0 + r) * IN_FT)[c4];
        reinterpret_cast<float4*>(&xs[r * XS_STRIDE])[c4] = v;
    }
    __syncthreads();

    const int jg = tid & 15;
    const int rg = tid >> 4;

    const float4 bv = reinterpret_cast<const float4*>(b)[jg];
    float acc[4][4];
#pragma unroll
    for (int rr = 0; rr < 4; ++rr) {
        acc[rr][0] = bv.x; acc[rr][1] = bv.y; acc[rr][2] = bv.z; acc[rr][3] = bv.w;
    }

    for (int k0 = 0; k0 < IN_FT; k0 += 4) {
        float wf[4][4];
#pragma unroll
        for (int kk = 0; kk < 4; ++kk) {
            const float4 t = *reinterpret_cast<const float4*>(&Wl[(k0 + kk) * OUT_FT + 4 * jg]);
            wf[kk][0] = t.x; wf[kk][1] = t.y; wf[kk][2] = t.z; wf[kk][3] = t.w;
        }
#pragma unroll
        for (int rr = 0; rr < 4; ++rr) {
            const float4 xv = *reinterpret_cast<const float4*>(&xs[(4 * rg + rr) * XS_STRIDE + k0]);
            const float xk[4] = {xv.x, xv.y, xv.z, xv.w};
#pragma unroll
            for (int kk = 0; kk < 4; ++kk)
#pragma unroll
                for (int jj = 0; jj < 4; ++jj)
                    acc[rr][jj] += xk[kk] * wf[kk][jj];
        }
    }

#pragma unroll
    for (int rr = 0; rr < 4; ++rr) {
        const int r = row0 + 4 * rg + rr;
        if (r < N)
            *reinterpret_cast<float4*>(&h[(size_t)r * OUT_FT + 4 * jg]) =
                make_float4(acc[rr][0], acc[rr][1], acc[rr][2], acc[rr][3]);
    }
}

// ===========================================================================
// CSR build v2: count+rank -> scan(3) -> fill (NO atomic, ONE 8B write/edge)
// ===========================================================================
__global__ __launch_bounds__(256) void k_count(
    const int* __restrict__ erow, int* __restrict__ cnt,
    int* __restrict__ rank, int E)
{
    const int e = blockIdx.x * blockDim.x + threadIdx.x;
    if (e < E) rank[e] = atomicAdd(&cnt[erow[e]], 1);   // rank write is coalesced
}

// chunk = 1024 elements/block; 256 threads x 4 elements each
__global__ __launch_bounds__(256) void k_scanA(
    const int* __restrict__ cnt, int* __restrict__ rptr,
    int* __restrict__ bsum, int N)
{
    __shared__ int s[256];
    const int t   = threadIdx.x;
    const int idx = blockIdx.x * 1024 + t * 4;

    int4 v = make_int4(0, 0, 0, 0);
    if (idx + 3 < N) v = *reinterpret_cast<const int4*>(&cnt[idx]);
    else {
        if (idx     < N) v.x = cnt[idx];
        if (idx + 1 < N) v.y = cnt[idx + 1];
        if (idx + 2 < N) v.z = cnt[idx + 2];
        if (idx + 3 < N) v.w = cnt[idx + 3];
    }
    const int tsum = v.x + v.y + v.z + v.w;
    s[t] = tsum;
    __syncthreads();
    for (int d = 1; d < 256; d <<= 1) {
        const int o = (t >= d) ? s[t - d] : 0;
        __syncthreads();
        s[t] += o;
        __syncthreads();
    }
    const int excl = s[t] - tsum;
    const int p0 = excl, p1 = p0 + v.x, p2 = p1 + v.y, p3 = p2 + v.z;
    if (idx     < N) rptr[idx]     = p0;
    if (idx + 1 < N) rptr[idx + 1] = p1;
    if (idx + 2 < N) rptr[idx + 2] = p2;
    if (idx + 3 < N) rptr[idx + 3] = p3;
    if (t == 255) bsum[blockIdx.x] = s[255];
}

__global__ __launch_bounds__(1024) void k_scanB(int* __restrict__ bsum, int nb)
{
    __shared__ int s[1024];
    const int t = threadIdx.x;
    const int v = (t < nb) ? bsum[t] : 0;
    s[t] = v;
    __syncthreads();
    for (int d = 1; d < 1024; d <<= 1) {
        const int o = (t >= d) ? s[t - d] : 0;
        __syncthreads();
        s[t] += o;
        __syncthreads();
    }
    if (t < nb) bsum[t] = s[t] - v;
}

__global__ __launch_bounds__(256) void k_scanC(
    int* __restrict__ rptr, const int* __restrict__ bsum, int N, int E)
{
    const int i = blockIdx.x * blockDim.x + threadIdx.x;
    if (i < N) rptr[i] += bsum[i >> 10];
    if (i == 0) rptr[N] = E;          // sentinel so gather can do rptr[r+1]-rptr[r]
}

__global__ __launch_bounds__(256) void k_fill2(
    const int* __restrict__ erow, const int* __restrict__ ecol,
    const float* __restrict__ eval_, const int* __restrict__ rptr,
    const int* __restrict__ rank, int2* __restrict__ colval, int E)
{
    const int e = blockIdx.x * blockDim.x + threadIdx.x;
    if (e >= E) return;
    const int r   = erow[e];
    const int pos = rptr[r] + rank[e];
    colval[pos] = make_int2(ecol[e], __float_as_int(eval_[e]));  // single 8B write
}

// ===========================================================================
// Gather: one wave per row, lane = feature. PReLU fused in epilogue.
// ===========================================================================
__global__ __launch_bounds__(256) void k_gather(
    const float* __restrict__ h, const int* __restrict__ rptr,
    const int2* __restrict__ colval, const float* __restrict__ alpha,
    float* __restrict__ out, int N)
{
    const int wid  = (int)((blockIdx.x * (size_t)blockDim.x + threadIdx.x) >> 6);
    const int lane = threadIdx.x & 63;
    if (wid >= N) return;

    const int start = rptr[wid];
    const int deg   = rptr[wid + 1] - start;

    float acc = 0.f;
    int j = 0;
    for (; j + 4 <= deg; j += 4) {
        const int2 cv0 = colval[start + j + 0];
        const int2 cv1 = colval[start + j + 1];
        const int2 cv2 = colval[start + j + 2];
        const int2 cv3 = colval[start + j + 3];
        const float h0 = h[(size_t)cv0.x * OUT_FT + lane];
        const float h1 = h[(size_t)cv1.x * OUT_FT + lane];
        const float h2 = h[(size_t)cv2.x * OUT_FT + lane];
        const float h3 = h[(size_t)cv3.x * OUT_FT + lane];
        acc += __int_as_float(cv0.y) * h0;
        acc += __int_as_float(cv1.y) * h1;
        acc += __int_as_float(cv2.y) * h2;
        acc += __int_as_float(cv3.y) * h3;
    }
    for (; j < deg; ++j) {
        const int2 cv = colval[start + j];
        acc += __int_as_float(cv.y) * h[(size_t)cv.x * OUT_FT + lane];
    }

    const float a = alpha[0];
    out[(size_t)wid * OUT_FT + lane] = (acc >= 0.f) ? acc : a * acc;
}

// ===========================================================================
// Fallback scatter (old atomic path) if ws too small for CSR
// ===========================================================================
__global__ __launch_bounds__(256) void gcn_scatter_kernel(
    const float* __restrict__ h, const int* __restrict__ erow,
    const int* __restrict__ ecol, const float* __restrict__ eval_,
    float* __restrict__ out, int E)
{
    const int t  = blockIdx.x * blockDim.x + threadIdx.x;
    const int e  = t >> 4;
    const int fg = (t & 15) * 4;
    if (e >= E) return;
    const int   col = ecol[e];
    const int   row = erow[e];
    const float v   = eval_[e];
    const float4 hv = *reinterpret_cast<const float4*>(&h[(size_t)col * OUT_FT + fg]);
    float* op = &out[(size_t)row * OUT_FT + fg];
    atomicAdd(op + 0, v * hv.x);
    atomicAdd(op + 1, v * hv.y);
    atomicAdd(op + 2, v * hv.z);
    atomicAdd(op + 3, v * hv.w);
}

__global__ __launch_bounds__(256) void gcn_prelu_kernel(
    float* __restrict__ out, const float* __restrict__ alpha, int n4)
{
    const float a = alpha[0];
    for (int i = blockIdx.x * blockDim.x + threadIdx.x; i < n4;
         i += gridDim.x * blockDim.x) {
        float4 v = reinterpret_cast<float4*>(out)[i];
        v.x = v.x >= 0.f ? v.x : a * v.x;
        v.y = v.y >= 0.f ? v.y : a * v.y;
        v.z = v.z >= 0.f ? v.z : a * v.z;
        v.w = v.w >= 0.f ? v.w : a * v.w;
        reinterpret_cast<float4*>(out)[i] = v;
    }
}

// ===========================================================================
extern "C" void kernel_launch(void* const* d_in, const int* in_sizes, int n_in,
                              void* d_out, int out_size, void* d_ws, size_t ws_size,
                              hipStream_t stream)
{
    const float* x     = (const float*)d_in[0];
    const float* W     = (const float*)d_in[1];
    const float* b     = (const float*)d_in[2];
    const float* alpha = (const float*)d_in[3];
    const int*   erow  = (const int*)d_in[4];
    const int*   ecol  = (const int*)d_in[5];
    const float* eval_ = (const float*)d_in[6];
    float* out = (float*)d_out;

    const int N = in_sizes[0] / IN_FT;   // 100000
    const int E = in_sizes[4];           // 1600000

    // ---- workspace layout ----
    // Persistent region: rptr (N+1 ints) + colval (E int2)
    // Union region B: phase1 {cnt, rank, bsum}  /  phase2 {h}
    // CSR build runs BEFORE fc so h can alias the dead cnt/rank/bsum arrays.
    auto al16 = [](size_t v) { return (v + 15) & ~15ull; };
    char* ws = (char*)d_ws;

    size_t off = 0;
    int*  rptr   = (int*)(ws + off);  off += al16((size_t)(N + 1) * sizeof(int));
    int2* colval = (int2*)(ws + off); off += al16((size_t)E * sizeof(int2));
    char* regB   = ws + off;

    const int nbA = (N + 1023) / 1024;
    const size_t phase1B = al16((size_t)N * sizeof(int))        // cnt
                         + al16((size_t)E * sizeof(int))        // rank
                         + al16((size_t)nbA * sizeof(int));     // bsum
    const size_t phase2B = (size_t)N * OUT_FT * sizeof(float);  // h
    const size_t regBsz  = phase1B > phase2B ? phase1B : phase2B;

    int*   cnt  = (int*)regB;
    int*   rank = (int*)(regB + al16((size_t)N * sizeof(int)));
    int*   bsum = (int*)(regB + al16((size_t)N * sizeof(int)) + al16((size_t)E * sizeof(int)));
    float* h    = (float*)regB;

    const bool csr_ok = (off + regBsz <= ws_size) && (nbA <= 1024);

    if (csr_ok) {
        // --- CSR build (uses regB as cnt/rank/bsum) ---
        hipMemsetAsync(cnt, 0, (size_t)N * sizeof(int), stream);
        k_count<<<(E + 255) / 256, 256, 0, stream>>>(erow, cnt, rank, E);
        k_scanA<<<nbA, 256, 0, stream>>>(cnt, rptr, bsum, N);
        k_scanB<<<1, 1024, 0, stream>>>(bsum, nbA);
        k_scanC<<<(N + 255) / 256, 256, 0, stream>>>(rptr, bsum, N, E);
        k_fill2<<<(E + 255) / 256, 256, 0, stream>>>(
            erow, ecol, eval_, rptr, rank, colval, E);

        // --- FC into regB (cnt/rank/bsum now dead) ---
        gcn_fc_kernel<<<(N + ROWS_PER_BLOCK - 1) / ROWS_PER_BLOCK, 256, 0, stream>>>(
            x, W, b, h, N);

        // --- Gather + PReLU ---
        const size_t gthreads = (size_t)N * 64;
        k_gather<<<(int)((gthreads + 255) / 256), 256, 0, stream>>>(
            h, rptr, colval, alpha, out, N);
    } else {
        float* hf = (float*)ws;  // fallback: h at ws base
        gcn_fc_kernel<<<(N + ROWS_PER_BLOCK - 1) / ROWS_PER_BLOCK, 256, 0, stream>>>(
            x, W, b, hf, N);
        hipMemsetAsync(d_out, 0, (size_t)N * OUT_FT * sizeof(float), stream);
        const long long st = (long long)E * 16;
        gcn_scatter_kernel<<<(st + 255) / 256, 256, 0, stream>>>(
            hf, erow, ecol, eval_, out, E);
        gcn_prelu_kernel<<<2048, 256, 0, stream>>>(out, alpha, (N * OUT_FT) / 4);
    }
}

// Round 5
// 300.273 us; speedup vs baseline: 4.9772x; 1.0491x over previous
//
#include <hip/hip_runtime.h>
#include <hip/hip_bf16.h>
#include <hip/hip_fp16.h>

#define IN_FT 128
#define OUT_FT 64

// ===========================================================================
// FC (main path): h = x @ W + b, h stored FP16 (halves gather traffic).
// fp32 accumulate on vector ALU — no fp32 MFMA on CDNA4.
// ===========================================================================
constexpr int ROWS_PER_BLOCK = 64;
constexpr int XS_STRIDE = 132;

__global__ __launch_bounds__(256) void gcn_fc_fp16_kernel(
    const float* __restrict__ x, const float* __restrict__ W,
    const float* __restrict__ b, __half* __restrict__ h, int N)
{
    __shared__ float Wl[IN_FT * OUT_FT];
    __shared__ float xs[ROWS_PER_BLOCK * XS_STRIDE];

    const int tid  = threadIdx.x;
    const int row0 = blockIdx.x * ROWS_PER_BLOCK;

    for (int i = tid; i < (IN_FT * OUT_FT) / 4; i += 256)
        reinterpret_cast<float4*>(Wl)[i] = reinterpret_cast<const float4*>(W)[i];

    for (int i = tid; i < (ROWS_PER_BLOCK * IN_FT) / 4; i += 256) {
        const int r  = i / (IN_FT / 4);
        const int c4 = i % (IN_FT / 4);
        float4 v = make_float4(0.f, 0.f, 0.f, 0.f);
        if (row0 + r < N)
            v = reinterpret_cast<const float4*>(x + (size_t)(row0 + r) * IN_FT)[c4];
        reinterpret_cast<float4*>(&xs[r * XS_STRIDE])[c4] = v;
    }
    __syncthreads();

    const int jg = tid & 15;
    const int rg = tid >> 4;

    const float4 bv = reinterpret_cast<const float4*>(b)[jg];
    float acc[4][4];
#pragma unroll
    for (int rr = 0; rr < 4; ++rr) {
        acc[rr][0] = bv.x; acc[rr][1] = bv.y; acc[rr][2] = bv.z; acc[rr][3] = bv.w;
    }

    for (int k0 = 0; k0 < IN_FT; k0 += 4) {
        float wf[4][4];
#pragma unroll
        for (int kk = 0; kk < 4; ++kk) {
            const float4 t = *reinterpret_cast<const float4*>(&Wl[(k0 + kk) * OUT_FT + 4 * jg]);
            wf[kk][0] = t.x; wf[kk][1] = t.y; wf[kk][2] = t.z; wf[kk][3] = t.w;
        }
#pragma unroll
        for (int rr = 0; rr < 4; ++rr) {
            const float4 xv = *reinterpret_cast<const float4*>(&xs[(4 * rg + rr) * XS_STRIDE + k0]);
            const float xk[4] = {xv.x, xv.y, xv.z, xv.w};
#pragma unroll
            for (int kk = 0; kk < 4; ++kk)
#pragma unroll
                for (int jj = 0; jj < 4; ++jj)
                    acc[rr][jj] += xk[kk] * wf[kk][jj];
        }
    }

#pragma unroll
    for (int rr = 0; rr < 4; ++rr) {
        const int r = row0 + 4 * rg + rr;
        if (r < N) {
            __half2 p0 = __floats2half2_rn(acc[rr][0], acc[rr][1]);
            __half2 p1 = __floats2half2_rn(acc[rr][2], acc[rr][3]);
            uint2 pk;
            pk.x = *reinterpret_cast<unsigned*>(&p0);
            pk.y = *reinterpret_cast<unsigned*>(&p1);
            *reinterpret_cast<uint2*>(&h[(size_t)r * OUT_FT + 4 * jg]) = pk;  // 8B store
        }
    }
}

// ===========================================================================
// FC (fallback path): fp32 h
// ===========================================================================
__global__ __launch_bounds__(256) void gcn_fc_kernel(
    const float* __restrict__ x, const float* __restrict__ W,
    const float* __restrict__ b, float* __restrict__ h, int N)
{
    __shared__ float Wl[IN_FT * OUT_FT];
    __shared__ float xs[ROWS_PER_BLOCK * XS_STRIDE];

    const int tid  = threadIdx.x;
    const int row0 = blockIdx.x * ROWS_PER_BLOCK;

    for (int i = tid; i < (IN_FT * OUT_FT) / 4; i += 256)
        reinterpret_cast<float4*>(Wl)[i] = reinterpret_cast<const float4*>(W)[i];

    for (int i = tid; i < (ROWS_PER_BLOCK * IN_FT) / 4; i += 256) {
        const int r  = i / (IN_FT / 4);
        const int c4 = i % (IN_FT / 4);
        float4 v = make_float4(0.f, 0.f, 0.f, 0.f);
        if (row0 + r < N)
            v = reinterpret_cast<const float4*>(x + (size_t)(row0 + r) * IN_FT)[c4];
        reinterpret_cast<float4*>(&xs[r * XS_STRIDE])[c4] = v;
    }
    __syncthreads();

    const int jg = tid & 15;
    const int rg = tid >> 4;

    const float4 bv = reinterpret_cast<const float4*>(b)[jg];
    float acc[4][4];
#pragma unroll
    for (int rr = 0; rr < 4; ++rr) {
        acc[rr][0] = bv.x; acc[rr][1] = bv.y; acc[rr][2] = bv.z; acc[rr][3] = bv.w;
    }

    for (int k0 = 0; k0 < IN_FT; k0 += 4) {
        float wf[4][4];
#pragma unroll
        for (int kk = 0; kk < 4; ++kk) {
            const float4 t = *reinterpret_cast<const float4*>(&Wl[(k0 + kk) * OUT_FT + 4 * jg]);
            wf[kk][0] = t.x; wf[kk][1] = t.y; wf[kk][2] = t.z; wf[kk][3] = t.w;
        }
#pragma unroll
        for (int rr = 0; rr < 4; ++rr) {
            const float4 xv = *reinterpret_cast<const float4*>(&xs[(4 * rg + rr) * XS_STRIDE + k0]);
            const float xk[4] = {xv.x, xv.y, xv.z, xv.w};
#pragma unroll
            for (int kk = 0; kk < 4; ++kk)
#pragma unroll
                for (int jj = 0; jj < 4; ++jj)
                    acc[rr][jj] += xk[kk] * wf[kk][jj];
        }
    }

#pragma unroll
    for (int rr = 0; rr < 4; ++rr) {
        const int r = row0 + 4 * rg + rr;
        if (r < N)
            *reinterpret_cast<float4*>(&h[(size_t)r * OUT_FT + 4 * jg]) =
                make_float4(acc[rr][0], acc[rr][1], acc[rr][2], acc[rr][3]);
    }
}

// ===========================================================================
// CSR build: count+rank (4 edges/thread) -> scan(3) -> fill (no atomic)
// ===========================================================================
__global__ __launch_bounds__(256) void k_count(
    const int* __restrict__ erow, int* __restrict__ cnt,
    int* __restrict__ rank, int E)
{
    const int e0 = (blockIdx.x * blockDim.x + threadIdx.x) * 4;
    if (e0 + 3 < E) {
        const int4 r4 = *reinterpret_cast<const int4*>(&erow[e0]);
        int4 k4;
        k4.x = atomicAdd(&cnt[r4.x], 1);
        k4.y = atomicAdd(&cnt[r4.y], 1);
        k4.z = atomicAdd(&cnt[r4.z], 1);
        k4.w = atomicAdd(&cnt[r4.w], 1);
        *reinterpret_cast<int4*>(&rank[e0]) = k4;   // coalesced 16B
    } else {
        for (int e = e0; e < E; ++e)
            rank[e] = atomicAdd(&cnt[erow[e]], 1);
    }
}

__global__ __launch_bounds__(256) void k_scanA(
    const int* __restrict__ cnt, int* __restrict__ rptr,
    int* __restrict__ bsum, int N)
{
    __shared__ int s[256];
    const int t   = threadIdx.x;
    const int idx = blockIdx.x * 1024 + t * 4;

    int4 v = make_int4(0, 0, 0, 0);
    if (idx + 3 < N) v = *reinterpret_cast<const int4*>(&cnt[idx]);
    else {
        if (idx     < N) v.x = cnt[idx];
        if (idx + 1 < N) v.y = cnt[idx + 1];
        if (idx + 2 < N) v.z = cnt[idx + 2];
        if (idx + 3 < N) v.w = cnt[idx + 3];
    }
    const int tsum = v.x + v.y + v.z + v.w;
    s[t] = tsum;
    __syncthreads();
    for (int d = 1; d < 256; d <<= 1) {
        const int o = (t >= d) ? s[t - d] : 0;
        __syncthreads();
        s[t] += o;
        __syncthreads();
    }
    const int excl = s[t] - tsum;
    const int p0 = excl, p1 = p0 + v.x, p2 = p1 + v.y, p3 = p2 + v.z;
    if (idx     < N) rptr[idx]     = p0;
    if (idx + 1 < N) rptr[idx + 1] = p1;
    if (idx + 2 < N) rptr[idx + 2] = p2;
    if (idx + 3 < N) rptr[idx + 3] = p3;
    if (t == 255) bsum[blockIdx.x] = s[255];
}

__global__ __launch_bounds__(1024) void k_scanB(int* __restrict__ bsum, int nb)
{
    __shared__ int s[1024];
    const int t = threadIdx.x;
    const int v = (t < nb) ? bsum[t] : 0;
    s[t] = v;
    __syncthreads();
    for (int d = 1; d < 1024; d <<= 1) {
        const int o = (t >= d) ? s[t - d] : 0;
        __syncthreads();
        s[t] += o;
        __syncthreads();
    }
    if (t < nb) bsum[t] = s[t] - v;
}

__global__ __launch_bounds__(256) void k_scanC(
    int* __restrict__ rptr, const int* __restrict__ bsum, int N, int E)
{
    const int i = blockIdx.x * blockDim.x + threadIdx.x;
    if (i < N) rptr[i] += bsum[i >> 10];
    if (i == 0) rptr[N] = E;
}

__global__ __launch_bounds__(256) void k_fill2(
    const int* __restrict__ erow, const int* __restrict__ ecol,
    const float* __restrict__ eval_, const int* __restrict__ rptr,
    const int* __restrict__ rank, int2* __restrict__ colval, int E)
{
    const int e0 = (blockIdx.x * blockDim.x + threadIdx.x) * 4;
    if (e0 + 3 < E) {
        const int4   r4 = *reinterpret_cast<const int4*>(&erow[e0]);
        const int4   c4 = *reinterpret_cast<const int4*>(&ecol[e0]);
        const float4 v4 = *reinterpret_cast<const float4*>(&eval_[e0]);
        const int4   k4 = *reinterpret_cast<const int4*>(&rank[e0]);
        colval[rptr[r4.x] + k4.x] = make_int2(c4.x, __float_as_int(v4.x));
        colval[rptr[r4.y] + k4.y] = make_int2(c4.y, __float_as_int(v4.y));
        colval[rptr[r4.z] + k4.z] = make_int2(c4.z, __float_as_int(v4.z));
        colval[rptr[r4.w] + k4.w] = make_int2(c4.w, __float_as_int(v4.w));
    } else {
        for (int e = e0; e < E; ++e)
            colval[rptr[erow[e]] + rank[e]] = make_int2(ecol[e], __float_as_int(eval_[e]));
    }
}

// ===========================================================================
// Gather (fp16 h): one wave per row, lane = feature. PReLU fused.
// ===========================================================================
__global__ __launch_bounds__(256) void k_gather(
    const __half* __restrict__ h, const int* __restrict__ rptr,
    const int2* __restrict__ colval, const float* __restrict__ alpha,
    float* __restrict__ out, int N)
{
    const int wid  = (int)((blockIdx.x * (size_t)blockDim.x + threadIdx.x) >> 6);
    const int lane = threadIdx.x & 63;
    if (wid >= N) return;

    const int start = rptr[wid];
    const int deg   = rptr[wid + 1] - start;

    float acc = 0.f;
    int j = 0;
    for (; j + 4 <= deg; j += 4) {
        const int2 cv0 = colval[start + j + 0];
        const int2 cv1 = colval[start + j + 1];
        const int2 cv2 = colval[start + j + 2];
        const int2 cv3 = colval[start + j + 3];
        const float h0 = __half2float(h[(size_t)cv0.x * OUT_FT + lane]);
        const float h1 = __half2float(h[(size_t)cv1.x * OUT_FT + lane]);
        const float h2 = __half2float(h[(size_t)cv2.x * OUT_FT + lane]);
        const float h3 = __half2float(h[(size_t)cv3.x * OUT_FT + lane]);
        acc += __int_as_float(cv0.y) * h0;
        acc += __int_as_float(cv1.y) * h1;
        acc += __int_as_float(cv2.y) * h2;
        acc += __int_as_float(cv3.y) * h3;
    }
    for (; j < deg; ++j) {
        const int2 cv = colval[start + j];
        acc += __int_as_float(cv.y) * __half2float(h[(size_t)cv.x * OUT_FT + lane]);
    }

    const float a = alpha[0];
    out[(size_t)wid * OUT_FT + lane] = (acc >= 0.f) ? acc : a * acc;
}

// ===========================================================================
// Fallback scatter (fp32 h) if ws too small for CSR
// ===========================================================================
__global__ __launch_bounds__(256) void gcn_scatter_kernel(
    const float* __restrict__ h, const int* __restrict__ erow,
    const int* __restrict__ ecol, const float* __restrict__ eval_,
    float* __restrict__ out, int E)
{
    const int t  = blockIdx.x * blockDim.x + threadIdx.x;
    const int e  = t >> 4;
    const int fg = (t & 15) * 4;
    if (e >= E) return;
    const int   col = ecol[e];
    const int   row = erow[e];
    const float v   = eval_[e];
    const float4 hv = *reinterpret_cast<const float4*>(&h[(size_t)col * OUT_FT + fg]);
    float* op = &out[(size_t)row * OUT_FT + fg];
    atomicAdd(op + 0, v * hv.x);
    atomicAdd(op + 1, v * hv.y);
    atomicAdd(op + 2, v * hv.z);
    atomicAdd(op + 3, v * hv.w);
}

__global__ __launch_bounds__(256) void gcn_prelu_kernel(
    float* __restrict__ out, const float* __restrict__ alpha, int n4)
{
    const float a = alpha[0];
    for (int i = blockIdx.x * blockDim.x + threadIdx.x; i < n4;
         i += gridDim.x * blockDim.x) {
        float4 v = reinterpret_cast<float4*>(out)[i];
        v.x = v.x >= 0.f ? v.x : a * v.x;
        v.y = v.y >= 0.f ? v.y : a * v.y;
        v.z = v.z >= 0.f ? v.z : a * v.z;
        v.w = v.w >= 0.f ? v.w : a * v.w;
        reinterpret_cast<float4*>(out)[i] = v;
    }
}

// ===========================================================================
extern "C" void kernel_launch(void* const* d_in, const int* in_sizes, int n_in,
                              void* d_out, int out_size, void* d_ws, size_t ws_size,
                              hipStream_t stream)
{
    const float* x     = (const float*)d_in[0];
    const float* W     = (const float*)d_in[1];
    const float* b     = (const float*)d_in[2];
    const float* alpha = (const float*)d_in[3];
    const int*   erow  = (const int*)d_in[4];
    const int*   ecol  = (const int*)d_in[5];
    const float* eval_ = (const float*)d_in[6];
    float* out = (float*)d_out;

    const int N = in_sizes[0] / IN_FT;   // 100000
    const int E = in_sizes[4];           // 1600000

    // ---- workspace layout ----
    // Persistent: rptr (N+1) + colval (E int2)
    // Union region B: phase1 {cnt, rank, bsum} / phase2 {h fp16}
    auto al16 = [](size_t v) { return (v + 15) & ~15ull; };
    char* ws = (char*)d_ws;

    size_t off = 0;
    int*  rptr   = (int*)(ws + off);  off += al16((size_t)(N + 1) * sizeof(int));
    int2* colval = (int2*)(ws + off); off += al16((size_t)E * sizeof(int2));
    char* regB   = ws + off;

    const int nbA = (N + 1023) / 1024;
    const size_t phase1B = al16((size_t)N * sizeof(int))
                         + al16((size_t)E * sizeof(int))
                         + al16((size_t)nbA * sizeof(int));
    const size_t phase2B = (size_t)N * OUT_FT * sizeof(__half);
    const size_t regBsz  = phase1B > phase2B ? phase1B : phase2B;

    int*    cnt  = (int*)regB;
    int*    rank = (int*)(regB + al16((size_t)N * sizeof(int)));
    int*    bsum = (int*)(regB + al16((size_t)N * sizeof(int)) + al16((size_t)E * sizeof(int)));
    __half* h16  = (__half*)regB;

    const bool csr_ok = (off + regBsz <= ws_size) && (nbA <= 1024);

    if (csr_ok) {
        // --- CSR build (regB = cnt/rank/bsum) ---
        hipMemsetAsync(cnt, 0, (size_t)N * sizeof(int), stream);
        k_count<<<(E / 4 + 255) / 256, 256, 0, stream>>>(erow, cnt, rank, E);
        k_scanA<<<nbA, 256, 0, stream>>>(cnt, rptr, bsum, N);
        k_scanB<<<1, 1024, 0, stream>>>(bsum, nbA);
        k_scanC<<<(N + 255) / 256, 256, 0, stream>>>(rptr, bsum, N, E);
        k_fill2<<<(E / 4 + 255) / 256, 256, 0, stream>>>(
            erow, ecol, eval_, rptr, rank, colval, E);

        // --- FC into regB as fp16 (cnt/rank/bsum now dead) ---
        gcn_fc_fp16_kernel<<<(N + ROWS_PER_BLOCK - 1) / ROWS_PER_BLOCK, 256, 0, stream>>>(
            x, W, b, h16, N);

        // --- Gather + PReLU ---
        const size_t gthreads = (size_t)N * 64;
        k_gather<<<(int)((gthreads + 255) / 256), 256, 0, stream>>>(
            h16, rptr, colval, alpha, out, N);
    } else {
        float* hf = (float*)ws;
        gcn_fc_kernel<<<(N + ROWS_PER_BLOCK - 1) / ROWS_PER_BLOCK, 256, 0, stream>>>(
            x, W, b, hf, N);
        hipMemsetAsync(d_out, 0, (size_t)N * OUT_FT * sizeof(float), stream);
        const long long st = (long long)E * 16;
        gcn_scatter_kernel<<<(st + 255) / 256, 256, 0, stream>>>(
            hf, erow, ecol, eval_, out, E);
        gcn_prelu_kernel<<<2048, 256, 0, stream>>>(out, alpha, (N * OUT_FT) / 4);
    }
}